// Round 8
// baseline (146.814 us; speedup 1.0000x reference)
//
#include <hip/hip_runtime.h>

#define N_TOT 65536
#define C_DIM 128
#define K_CB  1024
#define BN 64
#define BT 64
#define NTILE (K_CB / BT)
#define NBLK_D (N_TOT / BN)            // 1024 fused blocks

typedef __attribute__((ext_vector_type(8))) short bf16x8;   // 8 bf16 = 4 VGPR
typedef __attribute__((ext_vector_type(4))) float f32x4;

__device__ __forceinline__ ushort f2bf_rne(float f) {
  unsigned u = __float_as_uint(f);
  return (ushort)((u + 0x7FFFu + ((u >> 16) & 1u)) >> 16);
}

// med3u: inserting pk into sorted (t0<=t1<=t2) -> {min, med3, med3}: 3 VALU.
__device__ __forceinline__ unsigned med3u(unsigned a, unsigned b, unsigned c) {
  unsigned d;
  asm("v_med3_u32 %0, %1, %2, %3" : "=v"(d) : "v"(a), "v"(b), "v"(c));
  return d;
}

#define GLDS16(src, dst)                                                       \
  __builtin_amdgcn_global_load_lds(                                            \
      (const __attribute__((address_space(1))) void*)(src),                    \
      (__attribute__((address_space(3))) void*)(dst), 16, 0, 0)

// ---------------------------------------------------------------------------
// prep = cbsq (fp64 row sumsq, frozen math) + cbconv (bf16 RNE, same layout).
// NO global atomics (R3 lesson: 16384-way contended fp64 CAS = +400 µs).
// ---------------------------------------------------------------------------
__global__ __launch_bounds__(256) void prep_kernel(
    const float* __restrict__ cb, float* __restrict__ cbsq,
    ushort* __restrict__ cbh) {
  int w = threadIdx.x >> 6, lane = threadIdx.x & 63;
  int r = blockIdx.x * 4 + w;
  float2 v = reinterpret_cast<const float2*>(cb + (size_t)r * C_DIM)[lane];
  ushort2 h;
  h.x = f2bf_rne(v.x); h.y = f2bf_rne(v.y);
  reinterpret_cast<ushort2*>(cbh + (size_t)r * C_DIM)[lane] = h;
  double s = (double)v.x * (double)v.x + (double)v.y * (double)v.y;
#pragma unroll
  for (int off = 32; off >= 1; off >>= 1) s += __shfl_xor(s, off, 64);
  if (lane == 0) cbsq[r] = (float)s;
}

// ---------------------------------------------------------------------------
// FUSED dist+rescore, R8: zs hoist.
//  - R7 profile: rescore's fp64 j-loop is the largest VALU block; half of it
//    recomputes sum(z^2) per row — candidate-independent and already loaded
//    during z staging. Now: staging computes zsS[64]=fl32(fp64 row sumsq)
//    (8 FMA/thread + 4-step 16-lane xor reduce); rescore reads zsS[rl]
//    (broadcast) and drops the zsq half of the j-loop + 2 fp64 shuffles/it.
//  - rescore cbsq lookup moved to cbsqS (LDS copy still live).
//  - fp32 rounding points preserved: zs=fl32(fp64 sum any order — R5/R6
//    validated class), tt=fl32(2*p64), u=zs-tt, d=u+cbsq32, tie->low idx.
//  - dist section = R5 structure verbatim (validated R5-R7).
// ---------------------------------------------------------------------------
__global__ __launch_bounds__(256, 4) void dist_rescore_kernel(
    const float* __restrict__ ze, const ushort* __restrict__ cbh,
    const float* __restrict__ cbsq, const float* __restrict__ cb,
    float* __restrict__ zq, float* __restrict__ idx_f,
    double* __restrict__ partial) {
  // [B0 16K | B1 16K (zh aliases) | cbsq 4K | zsS 256B]; pool aliases B0+B1
  // head; candS @30720 (post-loop); shl @32768 (cbsqS dead by then... NO:
  // cbsqS used in rescore -> shl moved to 31744 (post-loop B1 tail, free)).
  __shared__ __align__(16) char smem[37120];
  char* const B0 = smem;
  char* const B1 = smem + 16384;
  ushort* zhS = reinterpret_cast<ushort*>(B1);            // [64][128] xor-swz
  unsigned* pool = reinterpret_cast<unsigned*>(smem);     // [64][97]
  float* const cbsqS = reinterpret_cast<float*>(smem + 32768);
  ushort* const candS = reinterpret_cast<ushort*>(smem + 30720);  // [64][8]
  double* const shl = reinterpret_cast<double*>(smem + 31744);    // [4]
  float* const zsS = reinterpret_cast<float*>(smem + 36864);      // [64]

  const int tid = threadIdx.x;
  const int w = tid >> 6, lane = tid & 63;
  const int mh = w & 1, nh = w >> 1;
  const int c16 = lane & 15, quad = lane >> 4;
  const int rowbase = blockIdx.x * BN;

  // Per-lane pre-swizzled source offsets for B staging (t-independent).
  int soff[4];
#pragma unroll
  for (int i = 0; i < 4; ++i) {
    int o = w * 4096 + i * 1024 + lane * 16;
    int row = o >> 8, inrow = o & 255;
    soff[i] = row * 256 + (inrow ^ ((row & 7) << 4));
  }
  const int stoff = w * 4096;   // wave-uniform LDS base within buffer

  // Tile-0 B stage into B0 (in flight across z staging; disjoint from zhS=B1).
#pragma unroll
  for (int i = 0; i < 4; ++i)
    GLDS16((const char*)cbh + soff[i], B0 + stoff + i * 1024);

  // Stage z tile -> bf16 LDS + per-row fp64 sumsq -> zsS (one time).
#pragma unroll
  for (int p = 0; p < 4; ++p) {
    int fid = p * 256 + tid;
    int row = fid >> 4, c8 = fid & 15;
    float4 a = reinterpret_cast<const float4*>(ze)[(size_t)(rowbase + row) * 32 + c8 * 2];
    float4 b = reinterpret_cast<const float4*>(ze)[(size_t)(rowbase + row) * 32 + c8 * 2 + 1];
    ushort h[8] = {f2bf_rne(a.x), f2bf_rne(a.y), f2bf_rne(a.z), f2bf_rne(a.w),
                   f2bf_rne(b.x), f2bf_rne(b.y), f2bf_rne(b.z), f2bf_rne(b.w)};
    *reinterpret_cast<uint4*>(&zhS[row * 128 + ((c8 ^ (row & 7)) * 8)]) =
        *reinterpret_cast<const uint4*>(h);
    // fp64 row sumsq: 16 consecutive lanes own one row -> 4-step xor reduce.
    double zq8 = ((double)a.x * (double)a.x + (double)a.y * (double)a.y) +
                 ((double)a.z * (double)a.z + (double)a.w * (double)a.w) +
                 ((double)b.x * (double)b.x + (double)b.y * (double)b.y) +
                 ((double)b.z * (double)b.z + (double)b.w * (double)b.w);
#pragma unroll
    for (int off = 1; off <= 8; off <<= 1) zq8 += __shfl_xor(zq8, off, 64);
    if (c8 == 0) zsS[row] = (float)zq8;
  }
  // cbsq -> LDS (1024 floats).
  reinterpret_cast<float4*>(cbsqS)[tid] = reinterpret_cast<const float4*>(cbsq)[tid];
  __syncthreads();   // #1: tile-0 B stage + z/zs writes + cbsq all visible

  // Hoist A-frags from zhS(=B1): afrag[m2][ks].
  const int xk = c16 & 7;
  bf16x8 afrag[2][4];
#pragma unroll
  for (int m2 = 0; m2 < 2; ++m2) {
    int r = (mh * 32 + m2 * 16 + c16) * 128;
#pragma unroll
    for (int ks = 0; ks < 4; ++ks)
      afrag[m2][ks] = *reinterpret_cast<const bf16x8*>(&zhS[r + ((ks * 4 + quad) ^ xk) * 8]);
  }
  __syncthreads();   // #2: zhS dead -> B1 stageable

  unsigned t3[8][3];
#pragma unroll
  for (int s = 0; s < 8; ++s) { t3[s][0] = 0xFFFFFFFFu; t3[s][1] = 0xFFFFFFFFu; t3[s][2] = 0xFFFFFFFFu; }

  const int cbase = nh * 32 + c16;

  auto STAGE = [&](int t, char* dst) {
#pragma unroll
    for (int i = 0; i < 4; ++i)
      GLDS16((const char*)cbh + (size_t)t * 16384 + soff[i], dst + stoff + i * 1024);
  };
  auto READ_MFMA = [&](const char* buf, f32x4 (&acc)[2][2]) {
    bf16x8 bf[2][4];
#pragma unroll
    for (int n2 = 0; n2 < 2; ++n2) {
      int rb = (nh * 32 + n2 * 16 + c16) * 256;
#pragma unroll
      for (int ks = 0; ks < 4; ++ks)
        bf[n2][ks] = *reinterpret_cast<const bf16x8*>(buf + rb + (((ks * 4 + quad) ^ xk) << 4));
    }
#pragma unroll
    for (int m2 = 0; m2 < 2; ++m2)
#pragma unroll
      for (int n2 = 0; n2 < 2; ++n2) acc[m2][n2] = (f32x4){0.f, 0.f, 0.f, 0.f};
#pragma unroll
    for (int ks = 0; ks < 4; ++ks)
#pragma unroll
      for (int m2 = 0; m2 < 2; ++m2)
#pragma unroll
        for (int n2 = 0; n2 < 2; ++n2)
          acc[m2][n2] = __builtin_amdgcn_mfma_f32_16x16x32_bf16(afrag[m2][ks], bf[n2][ks], acc[m2][n2], 0, 0, 0);
  };
  auto SORT = [&](const f32x4 (&acc)[2][2], int t) {
#pragma unroll
    for (int n2 = 0; n2 < 2; ++n2) {
      int code = t * BT + cbase + n2 * 16;
      unsigned codeu = (unsigned)code & 1023u;
      float csb = cbsqS[code] + 192.0f;
#pragma unroll
      for (int m2 = 0; m2 < 2; ++m2)
#pragma unroll
        for (int reg = 0; reg < 4; ++reg) {
          float kf = fmaf(-2.f, acc[m2][n2][reg], csb);
          unsigned pk = (__float_as_uint(kf) & 0xFFFFFC00u) | codeu;
          int s = m2 * 4 + reg;
          unsigned n0 = min(t3[s][0], pk);
          unsigned n1 = med3u(t3[s][0], t3[s][1], pk);
          unsigned n2v = med3u(t3[s][1], t3[s][2], pk);
          t3[s][0] = n0; t3[s][1] = n1; t3[s][2] = n2v;
        }
    }
  };

  f32x4 accA[2][2], accB[2][2];

  // tile 0 (B0 staged+drained at #1); stage tile 1 into B1.
  STAGE(1, B1);
  READ_MFMA(B0, accA);
  __syncthreads();   // #3: stage(1) drained; all B0 reads done

  for (int tp = 0; tp < 7; ++tp) {
    int t = 2 * tp + 1;                 // odd tile, lives in B1
    STAGE(t + 1, B0);                   // even tile -> B0
    SORT(accA, t - 1);                  // sort even tile t-1 (overlaps reads)
    READ_MFMA(B1, accB);                // tile t
    __syncthreads();
    STAGE(t + 2, B1);                   // odd tile -> B1
    SORT(accB, t);
    READ_MFMA(B0, accA);                // tile t+1
    __syncthreads();
  }
  // tiles 14 (accA, unsorted) and 15 (staged in B1, drained).
  SORT(accA, 14);
  READ_MFMA(B1, accB);
  SORT(accB, 15);
  __syncthreads();   // all waves done reading B0/B1 before pool overwrite

  // Pool: 32 (nh,c16) groups x top-3 = 96 packed keys per row.
#pragma unroll
  for (int s = 0; s < 8; ++s) {
    int row = mh * 32 + (s >> 2) * 16 + quad * 4 + (s & 3);
    int col = (nh * 16 + c16) * 3;
    pool[row * 97 + col] = t3[s][0];
    pool[row * 97 + col + 1] = t3[s][1];
    pool[row * 97 + col + 2] = t3[s][2];
  }
  __syncthreads();
  if (tid < BN) {
    unsigned k[8];
#pragma unroll
    for (int q = 0; q < 8; ++q) k[q] = 0xFFFFFFFFu;
    for (int p = 0; p < 96; ++p) {
      unsigned v = pool[tid * 97 + p];
      if (v < k[7]) {
        k[7] = v;
#pragma unroll
        for (int q = 7; q > 0; --q)
          if (k[q] < k[q - 1]) { unsigned tk = k[q]; k[q] = k[q - 1]; k[q - 1] = tk; }
      }
    }
    uint4 cw;
    cw.x = (k[0] & 1023u) | ((k[1] & 1023u) << 16);
    cw.y = (k[2] & 1023u) | ((k[3] & 1023u) << 16);
    cw.z = (k[4] & 1023u) | ((k[5] & 1023u) << 16);
    cw.w = (k[6] & 1023u) | ((k[7] & 1023u) << 16);
    reinterpret_cast<uint4*>(candS)[tid] = cw;   // LDS, not global
  }
  __syncthreads();   // candS visible to all waves

  // ---- rescore phase (half-wave scheme, zs from zsS, 8 iters x 8 rows) ----
  const int h2 = lane >> 5, sl = lane & 31;
  const int g = sl >> 2, e = sl & 3;
  double lacc = 0.0;
#pragma unroll 1
  for (int it = 0; it < 8; ++it) {
    int rl = it * 8 + w * 2 + h2;
    int row = rowbase + rl;
    int myc = candS[rl * 8 + g];
    float zs = zsS[rl];

    const float4* zr = reinterpret_cast<const float4*>(ze + (size_t)row * C_DIM);
    const float4* cr = reinterpret_cast<const float4*>(cb + (size_t)myc * C_DIM);

    double p0 = 0.0, p1 = 0.0;
#pragma unroll
    for (int j = 0; j < 8; ++j) {
      float4 zf = zr[e + 4 * j];
      float4 cf = cr[e + 4 * j];
      double a = ((double)zf.x * (double)cf.x + (double)zf.y * (double)cf.y) +
                 ((double)zf.z * (double)cf.z + (double)zf.w * (double)cf.w);
      if (j & 1) p1 += a; else p0 += a;
    }
    double pp = p0 + p1;
    pp += __shfl_xor(pp, 1, 64);
    pp += __shfl_xor(pp, 2, 64);

    float tt = (float)(2.0 * pp);
    float u = zs - tt;
    float d = u + cbsqS[myc];

    // Lexicographic (d, idx) xor min-reduce over the 8 groups of the half.
#pragma unroll
    for (int off = 4; off <= 16; off <<= 1) {
      float dg = __shfl_xor(d, off, 64);
      int ig = __shfl_xor(myc, off, 64);
      if (dg < d || (dg == d && ig < myc)) { d = dg; myc = ig; }
    }

    const float4* cbest = reinterpret_cast<const float4*>(cb + (size_t)myc * C_DIM);
    float4 cl = cbest[sl];
    float4 zl = zr[sl];
    reinterpret_cast<float4*>(zq + (size_t)row * C_DIM)[sl] = cl;

    double dx = (double)zl.x - (double)cl.x;
    double dy = (double)zl.y - (double)cl.y;
    double dz = (double)zl.z - (double)cl.z;
    double dw = (double)zl.w - (double)cl.w;
    double l = (dx * dx + dy * dy) + (dz * dz + dw * dw);
#pragma unroll
    for (int off = 1; off <= 32; off <<= 1) l += __shfl_xor(l, off, 64);
    lacc += l;   // rows rl(h2=0)+rl(h2=1) combined (stride-32 crossing)

    if (sl == 0) idx_f[row] = (float)myc;
  }

  if (lane == 0) shl[w] = lacc;
  __syncthreads();
  if (tid == 0)
    partial[blockIdx.x] = (shl[0] + shl[1]) + (shl[2] + shl[3]);
}

__global__ __launch_bounds__(256) void finalize_kernel(
    const double* __restrict__ partial, float* __restrict__ out_loss) {
  double s = 0.0;
  for (int i = threadIdx.x; i < NBLK_D; i += 256) s += partial[i];
#pragma unroll
  for (int off = 32; off >= 1; off >>= 1) s += __shfl_down(s, off, 64);
  __shared__ double sh[4];
  int wv = threadIdx.x >> 6, lane = threadIdx.x & 63;
  if (lane == 0) sh[wv] = s;
  __syncthreads();
  if (threadIdx.x == 0) {
    double tot = sh[0] + sh[1] + sh[2] + sh[3];
    double mse = tot / (double)((size_t)N_TOT * C_DIM);
    *out_loss = (float)(1.75 * mse);  // 0.75*q_latent + e_latent, both == mse
  }
}

// ---------------------------------------------------------------------------
extern "C" void kernel_launch(void* const* d_in, const int* in_sizes, int n_in,
                              void* d_out, int out_size, void* d_ws, size_t ws_size,
                              hipStream_t stream) {
  const float* ze = (const float*)d_in[0];
  const float* cb = (const float*)d_in[1];

  float* out = (float*)d_out;
  float* zq = out;                                   // [N*C]
  float* out_loss = out + (size_t)N_TOT * C_DIM;     // [1]
  float* idx_f = out_loss + 1;                       // [N]

  float* cbsq = (float*)d_ws;                             // 4 KB @0
  ushort* cbh = (ushort*)((char*)d_ws + 8192);            // 256 KB
  double* partial = (double*)((char*)d_ws + 270336);      // 8 KB

  prep_kernel<<<K_CB / 4, 256, 0, stream>>>(cb, cbsq, cbh);
  dist_rescore_kernel<<<NBLK_D, 256, 0, stream>>>(ze, cbh, cbsq, cb, zq,
                                                  idx_f, partial);
  finalize_kernel<<<1, 256, 0, stream>>>(partial, out_loss);
}

// Round 9
// 136.498 us; speedup vs baseline: 1.0756x; 1.0756x over previous
//
#include <hip/hip_runtime.h>

#define N_TOT 65536
#define C_DIM 128
#define K_CB  1024
#define BN 64
#define BT 64
#define NTILE (K_CB / BT)
#define NBLK_D (N_TOT / BN)            // 1024 fused blocks

typedef __attribute__((ext_vector_type(8))) short bf16x8;   // 8 bf16 = 4 VGPR
typedef __attribute__((ext_vector_type(4))) float f32x4;

__device__ __forceinline__ ushort f2bf_rne(float f) {
  unsigned u = __float_as_uint(f);
  return (ushort)((u + 0x7FFFu + ((u >> 16) & 1u)) >> 16);
}

// med3u: inserting pk into sorted (t0<=t1<=t2) -> {min, med3, med3}: 3 VALU.
__device__ __forceinline__ unsigned med3u(unsigned a, unsigned b, unsigned c) {
  unsigned d;
  asm("v_med3_u32 %0, %1, %2, %3" : "=v"(d) : "v"(a), "v"(b), "v"(c));
  return d;
}

#define GLDS16(src, dst)                                                       \
  __builtin_amdgcn_global_load_lds(                                            \
      (const __attribute__((address_space(1))) void*)(src),                    \
      (__attribute__((address_space(3))) void*)(dst), 16, 0, 0)

// ---------------------------------------------------------------------------
// prep = cbsq (fp64 row sumsq, frozen math) + cbconv (bf16 RNE, same layout).
// NO global atomics (R3 lesson: 16384-way contended fp64 CAS = +400 µs).
// ---------------------------------------------------------------------------
__global__ __launch_bounds__(256) void prep_kernel(
    const float* __restrict__ cb, float* __restrict__ cbsq,
    ushort* __restrict__ cbh) {
  int w = threadIdx.x >> 6, lane = threadIdx.x & 63;
  int r = blockIdx.x * 4 + w;
  float2 v = reinterpret_cast<const float2*>(cb + (size_t)r * C_DIM)[lane];
  ushort2 h;
  h.x = f2bf_rne(v.x); h.y = f2bf_rne(v.y);
  reinterpret_cast<ushort2*>(cbh + (size_t)r * C_DIM)[lane] = h;
  double s = (double)v.x * (double)v.x + (double)v.y * (double)v.y;
#pragma unroll
  for (int off = 32; off >= 1; off >>= 1) s += __shfl_xor(s, off, 64);
  if (lane == 0) cbsq[r] = (float)s;
}

// ---------------------------------------------------------------------------
// FUSED dist+rescore, R9 = R7 (verified 68 µs) + 4-bit B-swizzle.
//  - R8's zs hoist REVERTED: it induced scratch spill (+11 MB WRITE, +7 µs).
//  - Bank-conflict fix: old B involution used (row&7)<<4 (3-bit) -> read
//    chunk (kc)^(c16&7) occupied only 8/16 chunk slots -> 8 lanes per 4-bank
//    group, half the banks idle (2.42M conflict cycles, constant since R2).
//    New: source soff uses (row&15)<<4; read uses (kc ^ c16)<<4. Valid since
//    row&15 = c16 exactly (nh*32, n2*16 both ≡0 mod 16); bijective within
//    each 256B row. 4 lanes/chunk -> uniform-bank floor. Bit-identical math.
//  - A-side swizzle untouched ((row&7) matches its write, conflict-light,
//    one-time).
// ---------------------------------------------------------------------------
__global__ __launch_bounds__(256, 4) void dist_rescore_kernel(
    const float* __restrict__ ze, const ushort* __restrict__ cbh,
    const float* __restrict__ cbsq, const float* __restrict__ cb,
    float* __restrict__ zq, float* __restrict__ idx_f,
    double* __restrict__ partial) {
  // [B0 16K | B1 16K (zh aliases) | cbsq 4K]; pool[24832] aliases B0+B1 head;
  // candS @30720 (post-loop B1 tail); shl @31744 (post-loop B1 tail).
  __shared__ __align__(16) char smem[36864];
  char* const B0 = smem;
  char* const B1 = smem + 16384;
  ushort* zhS = reinterpret_cast<ushort*>(B1);            // [64][128] xor-swz
  unsigned* pool = reinterpret_cast<unsigned*>(smem);     // [64][97]
  float* const cbsqS = reinterpret_cast<float*>(smem + 32768);
  ushort* const candS = reinterpret_cast<ushort*>(smem + 30720);  // [64][8]
  double* const shl = reinterpret_cast<double*>(smem + 31744);    // [4]

  const int tid = threadIdx.x;
  const int w = tid >> 6, lane = tid & 63;
  const int mh = w & 1, nh = w >> 1;
  const int c16 = lane & 15, quad = lane >> 4;
  const int rowbase = blockIdx.x * BN;

  // Per-lane pre-swizzled source offsets for B staging (t-independent).
  // 4-bit involution: inrow ^ ((row&15)<<4), bijective within each 256B row.
  int soff[4];
#pragma unroll
  for (int i = 0; i < 4; ++i) {
    int o = w * 4096 + i * 1024 + lane * 16;
    int row = o >> 8, inrow = o & 255;
    soff[i] = row * 256 + (inrow ^ ((row & 15) << 4));
  }
  const int stoff = w * 4096;   // wave-uniform LDS base within buffer

  // Tile-0 B stage into B0 (in flight across z staging; disjoint from zhS=B1).
#pragma unroll
  for (int i = 0; i < 4; ++i)
    GLDS16((const char*)cbh + soff[i], B0 + stoff + i * 1024);

  // Stage z tile -> bf16 LDS (one time), into B1 region.
#pragma unroll
  for (int p = 0; p < 4; ++p) {
    int fid = p * 256 + tid;
    int row = fid >> 4, c8 = fid & 15;
    float4 a = reinterpret_cast<const float4*>(ze)[(size_t)(rowbase + row) * 32 + c8 * 2];
    float4 b = reinterpret_cast<const float4*>(ze)[(size_t)(rowbase + row) * 32 + c8 * 2 + 1];
    ushort h[8] = {f2bf_rne(a.x), f2bf_rne(a.y), f2bf_rne(a.z), f2bf_rne(a.w),
                   f2bf_rne(b.x), f2bf_rne(b.y), f2bf_rne(b.z), f2bf_rne(b.w)};
    *reinterpret_cast<uint4*>(&zhS[row * 128 + ((c8 ^ (row & 7)) * 8)]) =
        *reinterpret_cast<const uint4*>(h);
  }
  // cbsq -> LDS (1024 floats).
  reinterpret_cast<float4*>(cbsqS)[tid] = reinterpret_cast<const float4*>(cbsq)[tid];
  __syncthreads();   // #1: tile-0 B stage + z writes + cbsq all visible

  // Hoist A-frags from zhS(=B1): afrag[m2][ks].
  const int xk = c16 & 7;     // A-side involution (matches zhS write)
  const int xkb = c16;        // B-side 4-bit involution (matches soff)
  bf16x8 afrag[2][4];
#pragma unroll
  for (int m2 = 0; m2 < 2; ++m2) {
    int r = (mh * 32 + m2 * 16 + c16) * 128;
#pragma unroll
    for (int ks = 0; ks < 4; ++ks)
      afrag[m2][ks] = *reinterpret_cast<const bf16x8*>(&zhS[r + ((ks * 4 + quad) ^ xk) * 8]);
  }
  __syncthreads();   // #2: zhS dead -> B1 stageable

  unsigned t3[8][3];
#pragma unroll
  for (int s = 0; s < 8; ++s) { t3[s][0] = 0xFFFFFFFFu; t3[s][1] = 0xFFFFFFFFu; t3[s][2] = 0xFFFFFFFFu; }

  const int cbase = nh * 32 + c16;

  auto STAGE = [&](int t, char* dst) {
#pragma unroll
    for (int i = 0; i < 4; ++i)
      GLDS16((const char*)cbh + (size_t)t * 16384 + soff[i], dst + stoff + i * 1024);
  };
  auto READ_MFMA = [&](const char* buf, f32x4 (&acc)[2][2]) {
    bf16x8 bf[2][4];
#pragma unroll
    for (int n2 = 0; n2 < 2; ++n2) {
      int rb = (nh * 32 + n2 * 16 + c16) * 256;
#pragma unroll
      for (int ks = 0; ks < 4; ++ks)
        bf[n2][ks] = *reinterpret_cast<const bf16x8*>(buf + rb + (((ks * 4 + quad) ^ xkb) << 4));
    }
#pragma unroll
    for (int m2 = 0; m2 < 2; ++m2)
#pragma unroll
      for (int n2 = 0; n2 < 2; ++n2) acc[m2][n2] = (f32x4){0.f, 0.f, 0.f, 0.f};
#pragma unroll
    for (int ks = 0; ks < 4; ++ks)
#pragma unroll
      for (int m2 = 0; m2 < 2; ++m2)
#pragma unroll
        for (int n2 = 0; n2 < 2; ++n2)
          acc[m2][n2] = __builtin_amdgcn_mfma_f32_16x16x32_bf16(afrag[m2][ks], bf[n2][ks], acc[m2][n2], 0, 0, 0);
  };
  auto SORT = [&](const f32x4 (&acc)[2][2], int t) {
#pragma unroll
    for (int n2 = 0; n2 < 2; ++n2) {
      int code = t * BT + cbase + n2 * 16;
      unsigned codeu = (unsigned)code & 1023u;
      float csb = cbsqS[code] + 192.0f;
#pragma unroll
      for (int m2 = 0; m2 < 2; ++m2)
#pragma unroll
        for (int reg = 0; reg < 4; ++reg) {
          float kf = fmaf(-2.f, acc[m2][n2][reg], csb);
          unsigned pk = (__float_as_uint(kf) & 0xFFFFFC00u) | codeu;
          int s = m2 * 4 + reg;
          unsigned n0 = min(t3[s][0], pk);
          unsigned n1 = med3u(t3[s][0], t3[s][1], pk);
          unsigned n2v = med3u(t3[s][1], t3[s][2], pk);
          t3[s][0] = n0; t3[s][1] = n1; t3[s][2] = n2v;
        }
    }
  };

  f32x4 accA[2][2], accB[2][2];

  // tile 0 (B0 staged+drained at #1); stage tile 1 into B1.
  STAGE(1, B1);
  READ_MFMA(B0, accA);
  __syncthreads();   // #3: stage(1) drained; all B0 reads done

  for (int tp = 0; tp < 7; ++tp) {
    int t = 2 * tp + 1;                 // odd tile, lives in B1
    STAGE(t + 1, B0);                   // even tile -> B0
    SORT(accA, t - 1);                  // sort even tile t-1 (overlaps reads)
    READ_MFMA(B1, accB);                // tile t
    __syncthreads();
    STAGE(t + 2, B1);                   // odd tile -> B1
    SORT(accB, t);
    READ_MFMA(B0, accA);                // tile t+1
    __syncthreads();
  }
  // tiles 14 (accA, unsorted) and 15 (staged in B1, drained).
  SORT(accA, 14);
  READ_MFMA(B1, accB);
  SORT(accB, 15);
  __syncthreads();   // all waves done reading B0/B1 before pool overwrite

  // Pool: 32 (nh,c16) groups x top-3 = 96 packed keys per row.
#pragma unroll
  for (int s = 0; s < 8; ++s) {
    int row = mh * 32 + (s >> 2) * 16 + quad * 4 + (s & 3);
    int col = (nh * 16 + c16) * 3;
    pool[row * 97 + col] = t3[s][0];
    pool[row * 97 + col + 1] = t3[s][1];
    pool[row * 97 + col + 2] = t3[s][2];
  }
  __syncthreads();
  if (tid < BN) {
    unsigned k[8];
#pragma unroll
    for (int q = 0; q < 8; ++q) k[q] = 0xFFFFFFFFu;
    for (int p = 0; p < 96; ++p) {
      unsigned v = pool[tid * 97 + p];
      if (v < k[7]) {
        k[7] = v;
#pragma unroll
        for (int q = 7; q > 0; --q)
          if (k[q] < k[q - 1]) { unsigned tk = k[q]; k[q] = k[q - 1]; k[q - 1] = tk; }
      }
    }
    uint4 cw;
    cw.x = (k[0] & 1023u) | ((k[1] & 1023u) << 16);
    cw.y = (k[2] & 1023u) | ((k[3] & 1023u) << 16);
    cw.z = (k[4] & 1023u) | ((k[5] & 1023u) << 16);
    cw.w = (k[6] & 1023u) | ((k[7] & 1023u) << 16);
    reinterpret_cast<uint4*>(candS)[tid] = cw;   // LDS, not global
  }
  __syncthreads();   // candS visible to all waves

  // ---- rescore phase (R6/R7 half-wave scheme, 8 iters x 8 rows) ----
  const int h2 = lane >> 5, sl = lane & 31;
  const int g = sl >> 2, e = sl & 3;
  double lacc = 0.0;
#pragma unroll 1
  for (int it = 0; it < 8; ++it) {
    int rl = it * 8 + w * 2 + h2;
    int row = rowbase + rl;
    int myc = candS[rl * 8 + g];

    const float4* zr = reinterpret_cast<const float4*>(ze + (size_t)row * C_DIM);
    const float4* cr = reinterpret_cast<const float4*>(cb + (size_t)myc * C_DIM);

    double p0 = 0.0, p1 = 0.0, zs0 = 0.0, zs1 = 0.0;
#pragma unroll
    for (int j = 0; j < 8; ++j) {
      float4 zf = zr[e + 4 * j];
      float4 cf = cr[e + 4 * j];
      double a = ((double)zf.x * (double)cf.x + (double)zf.y * (double)cf.y) +
                 ((double)zf.z * (double)cf.z + (double)zf.w * (double)cf.w);
      double b = ((double)zf.x * (double)zf.x + (double)zf.y * (double)zf.y) +
                 ((double)zf.z * (double)zf.z + (double)zf.w * (double)zf.w);
      if (j & 1) { p1 += a; zs1 += b; } else { p0 += a; zs0 += b; }
    }
    double pp = p0 + p1;
    double zsum = zs0 + zs1;
    pp += __shfl_xor(pp, 1, 64);
    pp += __shfl_xor(pp, 2, 64);
    zsum += __shfl_xor(zsum, 1, 64);
    zsum += __shfl_xor(zsum, 2, 64);

    float zs = (float)zsum;
    float tt = (float)(2.0 * pp);
    float u = zs - tt;
    float d = u + cbsq[myc];

    // Lexicographic (d, idx) xor min-reduce over the 8 groups of the half.
#pragma unroll
    for (int off = 4; off <= 16; off <<= 1) {
      float dg = __shfl_xor(d, off, 64);
      int ig = __shfl_xor(myc, off, 64);
      if (dg < d || (dg == d && ig < myc)) { d = dg; myc = ig; }
    }

    const float4* cbest = reinterpret_cast<const float4*>(cb + (size_t)myc * C_DIM);
    float4 cl = cbest[sl];
    float4 zl = zr[sl];
    reinterpret_cast<float4*>(zq + (size_t)row * C_DIM)[sl] = cl;

    double dx = (double)zl.x - (double)cl.x;
    double dy = (double)zl.y - (double)cl.y;
    double dz = (double)zl.z - (double)cl.z;
    double dw = (double)zl.w - (double)cl.w;
    double l = (dx * dx + dy * dy) + (dz * dz + dw * dw);
#pragma unroll
    for (int off = 1; off <= 32; off <<= 1) l += __shfl_xor(l, off, 64);
    lacc += l;   // rows rl(h2=0)+rl(h2=1) combined (stride-32 crossing)

    if (sl == 0) idx_f[row] = (float)myc;
  }

  if (lane == 0) shl[w] = lacc;
  __syncthreads();
  if (tid == 0)
    partial[blockIdx.x] = (shl[0] + shl[1]) + (shl[2] + shl[3]);
}

__global__ __launch_bounds__(256) void finalize_kernel(
    const double* __restrict__ partial, float* __restrict__ out_loss) {
  double s = 0.0;
  for (int i = threadIdx.x; i < NBLK_D; i += 256) s += partial[i];
#pragma unroll
  for (int off = 32; off >= 1; off >>= 1) s += __shfl_down(s, off, 64);
  __shared__ double sh[4];
  int wv = threadIdx.x >> 6, lane = threadIdx.x & 63;
  if (lane == 0) sh[wv] = s;
  __syncthreads();
  if (threadIdx.x == 0) {
    double tot = sh[0] + sh[1] + sh[2] + sh[3];
    double mse = tot / (double)((size_t)N_TOT * C_DIM);
    *out_loss = (float)(1.75 * mse);  // 0.75*q_latent + e_latent, both == mse
  }
}

// ---------------------------------------------------------------------------
extern "C" void kernel_launch(void* const* d_in, const int* in_sizes, int n_in,
                              void* d_out, int out_size, void* d_ws, size_t ws_size,
                              hipStream_t stream) {
  const float* ze = (const float*)d_in[0];
  const float* cb = (const float*)d_in[1];

  float* out = (float*)d_out;
  float* zq = out;                                   // [N*C]
  float* out_loss = out + (size_t)N_TOT * C_DIM;     // [1]
  float* idx_f = out_loss + 1;                       // [N]

  float* cbsq = (float*)d_ws;                             // 4 KB @0
  ushort* cbh = (ushort*)((char*)d_ws + 8192);            // 256 KB
  double* partial = (double*)((char*)d_ws + 270336);      // 8 KB

  prep_kernel<<<K_CB / 4, 256, 0, stream>>>(cb, cbsq, cbh);
  dist_rescore_kernel<<<NBLK_D, 256, 0, stream>>>(ze, cbh, cbsq, cb, zq,
                                                  idx_f, partial);
  finalize_kernel<<<1, 256, 0, stream>>>(partial, out_loss);
}